// Round 1
// 1374.994 us; speedup vs baseline: 1.0955x; 1.0955x over previous
//
#include <hip/hip_runtime.h>

typedef __attribute__((ext_vector_type(4))) float floatx4;
typedef __attribute__((ext_vector_type(8))) short short8;

// BATCH=256, SEQ=64, HEADS=64, HEAD_DIM=64, EMBED=4096
// P layout: [n][k][h][q], 256*64*64*64 bf16 = 134,217,728 B (reused as F by pv_k)

__device__ __forceinline__ unsigned short f2bf(float x) {
    union { float f; unsigned u; } v; v.f = x;
    unsigned r = v.u + 0x7FFFu + ((v.u >> 16) & 1u);
    return (unsigned short)(r >> 16);
}
__device__ __forceinline__ float bf2f(unsigned short h) {
    union { unsigned u; float f; } v; v.u = ((unsigned)h) << 16; return v.f;
}
__device__ __forceinline__ unsigned pk2(float a, float b) {
    return (unsigned)f2bf(a) | ((unsigned)f2bf(b) << 16);
}

// ---------------- K1: cast w_out (4096x4096 f32) -> bf16 ----------------
__global__ void cast_w(const float* __restrict__ w, unsigned short* __restrict__ wb) {
    size_t i = ((size_t)blockIdx.x * 256 + threadIdx.x) * 4;
    float4 v = *(const float4*)(w + i);
    ushort4 o;
    o.x = f2bf(v.x); o.y = f2bf(v.y); o.z = f2bf(v.z); o.w = f2bf(v.w);
    *(ushort4*)(wb + i) = o;
}

// ---------------- K2: Vsum[n,h,d] = sum_vh values[n,h,vh*64+d] ----------------
__global__ void vsum_k(const float* __restrict__ values, float* __restrict__ vsum) {
    const int t = threadIdx.x;
    const int d = t & 63;
    const int nh = blockIdx.x * 4 + (t >> 6);   // n*64+h
    const float* base = values + (size_t)nh * 4096 + d;
    float acc = 0.f;
    #pragma unroll
    for (int vh = 0; vh < 64; vh++) acc += base[vh * 64];
    vsum[(size_t)nh * 64 + d] = acc;
}

// ---------------- K3 v2: MFMA energy. Et[k,q] = K.Q^T per (n,h); P=exp(E/8) ----
union U16 { uint4 u; short8 s; };

__global__ __launch_bounds__(256) void energy_k2(const float* __restrict__ query,
        const float* __restrict__ keys, const int* __restrict__ mask,
        unsigned short* __restrict__ P) {
    __shared__ __align__(16) unsigned short T[64 * 256];   // [k][h4*64+q] 32 KB
    const int n = blockIdx.y;
    const int hq = blockIdx.x;
    const int t = threadIdx.x;
    const int w = t >> 6, l = t & 63;
    const int r16 = l & 15, quad = l >> 4;
    const int kw = w >> 1, qw = w & 1;
    unsigned short* Pn = P + (size_t)n * 262144;

    for (int hc = 0; hc < 4; hc++) {
        const int h0 = hq * 16 + hc * 4;
        for (int h4 = 0; h4 < 4; h4++) {
            const int h = h0 + h4;
            if (mask[n * 64 + h] == 0) {
                #pragma unroll
                for (int mi = 0; mi < 2; mi++)
                    #pragma unroll
                    for (int ni = 0; ni < 2; ni++)
                        #pragma unroll
                        for (int r = 0; r < 4; r++)
                            T[(kw*32 + mi*16 + quad*4 + r) * 256 + h4*64
                              + qw*32 + ni*16 + r16] = 0;
                continue;
            }
            const float* Qr = query + ((size_t)n * 64 + h) * 4096;
            const float* Kr = keys  + ((size_t)n * 64 + h) * 4096;
            short8 af[2][2], bf[2][2];
            #pragma unroll
            for (int mi = 0; mi < 2; mi++)
                #pragma unroll
                for (int ks = 0; ks < 2; ks++) {
                    const float* src = Kr + (kw*32 + mi*16 + r16) * 64 + ks*32 + quad*8;
                    float4 x = *(const float4*)src;
                    float4 y = *(const float4*)(src + 4);
                    U16 u; u.u.x = pk2(x.x, x.y); u.u.y = pk2(x.z, x.w);
                    u.u.z = pk2(y.x, y.y); u.u.w = pk2(y.z, y.w);
                    af[mi][ks] = u.s;
                }
            #pragma unroll
            for (int ni = 0; ni < 2; ni++)
                #pragma unroll
                for (int ks = 0; ks < 2; ks++) {
                    const float* src = Qr + (qw*32 + ni*16 + r16) * 64 + ks*32 + quad*8;
                    float4 x = *(const float4*)src;
                    float4 y = *(const float4*)(src + 4);
                    U16 u; u.u.x = pk2(x.x, x.y); u.u.y = pk2(x.z, x.w);
                    u.u.z = pk2(y.x, y.y); u.u.w = pk2(y.z, y.w);
                    bf[ni][ks] = u.s;
                }
            floatx4 acc[2][2];
            #pragma unroll
            for (int mi = 0; mi < 2; mi++)
                #pragma unroll
                for (int ni = 0; ni < 2; ni++) acc[mi][ni] = (floatx4)(0.f);
            #pragma unroll
            for (int ks = 0; ks < 2; ks++)
                #pragma unroll
                for (int mi = 0; mi < 2; mi++)
                    #pragma unroll
                    for (int ni = 0; ni < 2; ni++)
                        acc[mi][ni] = __builtin_amdgcn_mfma_f32_16x16x32_bf16(
                            af[mi][ks], bf[ni][ks], acc[mi][ni], 0, 0, 0);
            #pragma unroll
            for (int mi = 0; mi < 2; mi++)
                #pragma unroll
                for (int ni = 0; ni < 2; ni++)
                    #pragma unroll
                    for (int r = 0; r < 4; r++) {
                        float p = __expf(acc[mi][ni][r] * 0.125f);
                        T[(kw*32 + mi*16 + quad*4 + r) * 256 + h4*64
                          + qw*32 + ni*16 + r16] = f2bf(p);
                    }
        }
        __syncthreads();
        #pragma unroll
        for (int i = 0; i < 8; i++) {
            int s = i * 256 + t;            // uint4 id, 0..2047
            int k = s >> 5, u = s & 31;
            uint4 v = ((const uint4*)T)[s];
            *(uint4*)(Pn + (size_t)k * 4096 + h0 * 64 + u * 8) = v;
        }
        __syncthreads();
    }
}

// ---------------- K3b: denom[j] = sum_n P[n*262144 + j]  (j over [k][h][q]) ---
__global__ __launch_bounds__(256) void denom_k(const unsigned short* __restrict__ P,
        float* __restrict__ denom) {
    const int j0 = (blockIdx.x * 256 + threadIdx.x) * 4;
    const unsigned short* p = P + j0;
    float s0 = 0.f, s1 = 0.f, s2 = 0.f, s3 = 0.f;
    #pragma unroll 8
    for (int n = 0; n < 256; n++) {
        uint2 v = *(const uint2*)(p + (size_t)n * 262144);
        s0 += bf2f((unsigned short)(v.x & 0xffff));
        s1 += bf2f((unsigned short)(v.x >> 16));
        s2 += bf2f((unsigned short)(v.y & 0xffff));
        s3 += bf2f((unsigned short)(v.y >> 16));
    }
    float4 o; o.x = s0; o.y = s1; o.z = s2; o.w = s3;
    *(float4*)(denom + j0) = o;
}

// ---------------- K4: normalize + PV; writes F in-place over P slice ----------
#define VSD 68
__global__ __launch_bounds__(256) void pv_k(const unsigned short* P_in,
        const float* __restrict__ denom, const float* __restrict__ vsum,
        unsigned short* F) {
    __shared__ __align__(16) unsigned short attn[4 * 64 * 64];  // [b][h][q] bf16
    __shared__ __align__(16) float Vs[64 * VSD];                // [h][d]
    const int kg4 = blockIdx.x;
    const int n = blockIdx.y;
    const int t = threadIdx.x;
    #pragma unroll
    for (int i = 0; i < 4; i++) {
        int v = i * 256 + t;
        float4 x = *(const float4*)(vsum + (size_t)n * 4096 + (size_t)v * 4);
        int hh = v >> 4, d0 = (v & 15) * 4;
        *(float4*)(Vs + hh * VSD + d0) = x;
    }
    const size_t slice = ((size_t)n * 64 + kg4 * 4) * 4096;
    const uint4* Pv = (const uint4*)(P_in + slice);
    const float* dsl = denom + (size_t)kg4 * 4 * 4096;
    uint4* Av = (uint4*)attn;
    #pragma unroll
    for (int i = 0; i < 8; i++) {
        int j = i * 256 + t;
        uint4 raw = Pv[j];
        floatx4 d0 = *(const floatx4*)(dsl + (size_t)j * 8);
        floatx4 d1 = *(const floatx4*)(dsl + (size_t)j * 8 + 4);
        float v0 = bf2f((unsigned short)(raw.x & 0xffff)) * __builtin_amdgcn_rcpf(d0.x);
        float v1 = bf2f((unsigned short)(raw.x >> 16))    * __builtin_amdgcn_rcpf(d0.y);
        float v2 = bf2f((unsigned short)(raw.y & 0xffff)) * __builtin_amdgcn_rcpf(d0.z);
        float v3 = bf2f((unsigned short)(raw.y >> 16))    * __builtin_amdgcn_rcpf(d0.w);
        float v4 = bf2f((unsigned short)(raw.z & 0xffff)) * __builtin_amdgcn_rcpf(d1.x);
        float v5 = bf2f((unsigned short)(raw.z >> 16))    * __builtin_amdgcn_rcpf(d1.y);
        float v6 = bf2f((unsigned short)(raw.w & 0xffff)) * __builtin_amdgcn_rcpf(d1.z);
        float v7 = bf2f((unsigned short)(raw.w >> 16))    * __builtin_amdgcn_rcpf(d1.w);
        uint4 o;
        o.x = pk2(v0, v1); o.y = pk2(v2, v3); o.z = pk2(v4, v5); o.w = pk2(v6, v7);
        Av[j] = o;
    }
    __syncthreads();
    const int qq = t >> 2, dsub = t & 3;
    floatx4 acc[4][4];
    #pragma unroll
    for (int b = 0; b < 4; b++)
        #pragma unroll
        for (int m = 0; m < 4; m++) acc[b][m] = (floatx4)(0.f);
    #pragma unroll 4
    for (int h = 0; h < 64; h++) {
        float a0 = bf2f(attn[(0 * 64 + h) * 64 + qq]);
        float a1 = bf2f(attn[(1 * 64 + h) * 64 + qq]);
        float a2 = bf2f(attn[(2 * 64 + h) * 64 + qq]);
        float a3 = bf2f(attn[(3 * 64 + h) * 64 + qq]);
        floatx4 w0 = *(const floatx4*)(Vs + h * VSD + dsub * 16);
        floatx4 w1 = *(const floatx4*)(Vs + h * VSD + dsub * 16 + 4);
        floatx4 w2 = *(const floatx4*)(Vs + h * VSD + dsub * 16 + 8);
        floatx4 w3 = *(const floatx4*)(Vs + h * VSD + dsub * 16 + 12);
        acc[0][0] += a0 * w0; acc[0][1] += a0 * w1; acc[0][2] += a0 * w2; acc[0][3] += a0 * w3;
        acc[1][0] += a1 * w0; acc[1][1] += a1 * w1; acc[1][2] += a1 * w2; acc[1][3] += a1 * w3;
        acc[2][0] += a2 * w0; acc[2][1] += a2 * w1; acc[2][2] += a2 * w2; acc[2][3] += a2 * w3;
        acc[3][0] += a3 * w0; acc[3][1] += a3 * w1; acc[3][2] += a3 * w2; acc[3][3] += a3 * w3;
    }
    #pragma unroll
    for (int b = 0; b < 4; b++) {
        size_t base = ((size_t)n * 64 + kg4 * 4 + b) * 4096 + qq * 64 + dsub * 16;
        uint4 o0, o1;
        o0.x = pk2(acc[b][0].x, acc[b][0].y); o0.y = pk2(acc[b][0].z, acc[b][0].w);
        o0.z = pk2(acc[b][1].x, acc[b][1].y); o0.w = pk2(acc[b][1].z, acc[b][1].w);
        o1.x = pk2(acc[b][2].x, acc[b][2].y); o1.y = pk2(acc[b][2].z, acc[b][2].w);
        o1.z = pk2(acc[b][3].x, acc[b][3].y); o1.w = pk2(acc[b][3].z, acc[b][3].w);
        *(uint4*)(F + base) = o0;
        *(uint4*)(F + base + 8) = o1;
    }
}

// ---------------- K5 v2: Y = F @ W^T + b, 256x256 8-phase bf16 MFMA GEMM -------
// m201-style template: 8 waves (2Mx4N), BK=64 as two K=32 halves, 128 KiB LDS
// double-buffer, XOR-swizzle (pre-swizzled stage SOURCE + swizzled ds_read,
// linear gload_lds dest), one counted vmcnt(6) per K-tile, setprio(1) around
// each 16-MFMA cluster, XCD-aware block swizzle. Schedule (verified on paper):
//   phase0: rd A[qm0,k0]+B[k0];  stage A-k1(tt+1)   [other buffer]
//   phase1: rd A[qm1,k0];        stage B-k0(tt+2)   [region freed ph0]
//   phase2: rd A[qm0,k1]+B[k1];  stage A-k0(tt+2)   [region freed ph1]
//   phase3: rd A[qm1,k1];        stage B-k1(tt+2); vmcnt(6)  [freed ph2]
// At each tile-end vmcnt(6): the 3 newest half-tiles stay in flight; everything
// needed by tile tt+1 was issued >=4 stages earlier => complete. K-order of
// accumulation matches the old kernel exactly (bit-identical output).

#define STAGE(mat, kh, tt2) do {                                               \
    const unsigned short* g_ = ((mat) ? pB : pA) + (tt2) * 64 + (kh) * 32;     \
    unsigned short* d_ = Lb + (((tt2) & 1) * 32768) + (mat) * 16384            \
                            + (kh) * 8192 + lw;                                \
    __builtin_amdgcn_global_load_lds(                                          \
        (const __attribute__((address_space(1))) unsigned int*)g_,             \
        (__attribute__((address_space(3))) unsigned int*)d_, 16, 0, 0);        \
    __builtin_amdgcn_global_load_lds(                                          \
        (const __attribute__((address_space(1))) unsigned int*)(g_ + 128*4096),\
        (__attribute__((address_space(3))) unsigned int*)(d_ + 4096), 16, 0, 0);\
  } while (0)

#define RD_A(qm, ks) do {                                                      \
    const unsigned short* Ar_ = Lb + buf * 32768 + (ks) * 8192 + cx8;          \
    _Pragma("unroll") for (int mi_ = 0; mi_ < 4; mi_++)                        \
      a[mi_] = *(const short8*)(Ar_ + (arow0 + (qm)*64 + mi_*16) * 32);        \
  } while (0)

#define RD_B(ks) do {                                                          \
    const unsigned short* Br_ = Lb + buf * 32768 + 16384 + (ks) * 8192 + cx8;  \
    _Pragma("unroll") for (int ni_ = 0; ni_ < 4; ni_++)                        \
      b[ni_] = *(const short8*)(Br_ + (brow0 + ni_*16) * 32);                  \
  } while (0)

#define MFMA_PH(qm) do {                                                       \
    __builtin_amdgcn_s_barrier();                                              \
    asm volatile("s_waitcnt lgkmcnt(0)" ::: "memory");                         \
    __builtin_amdgcn_sched_barrier(0);                                         \
    __builtin_amdgcn_s_setprio(1);                                             \
    _Pragma("unroll") for (int mi_ = 0; mi_ < 4; mi_++)                        \
      _Pragma("unroll") for (int ni_ = 0; ni_ < 4; ni_++)                      \
        acc[(qm)*4 + mi_][ni_] = __builtin_amdgcn_mfma_f32_16x16x32_bf16(      \
            a[mi_], b[ni_], acc[(qm)*4 + mi_][ni_], 0, 0, 0);                  \
    __builtin_amdgcn_s_setprio(0);                                             \
    __builtin_amdgcn_s_barrier();                                              \
  } while (0)

__global__ __launch_bounds__(512, 2) void gemm_bt2(const unsigned short* __restrict__ A,
        const unsigned short* __restrict__ B, const float* __restrict__ bias,
        float* __restrict__ C) {
    __shared__ __align__(16) unsigned short Lb[65536];   // 128 KiB
    const int t = threadIdx.x;
    const int w = t >> 6, l = t & 63;
    const int r16 = l & 15, quad = l >> 4;
    const int wm = w >> 2, wn = w & 3;

    const int bid = blockIdx.x;
    const int s = ((bid & 7) << 7) | (bid >> 3);  // bijective XCD swizzle, nwg=1024
    const int m0 = (s >> 4) << 8;
    const int n0 = (s & 15) << 8;

    // stage-lane geometry (source pre-swizzled by involution x ^= ((x>>6)&3)<<4)
    const int srow = w * 16 + (l >> 2);
    const int kcol = (((l & 3) ^ ((l >> 2) & 3)) << 3);
    const unsigned short* pA = A + (size_t)(m0 + srow) * 4096 + kcol;
    const unsigned short* pB = B + (size_t)(n0 + srow) * 4096 + kcol;
    const int lw = w * 512;                        // wave-uniform LDS base (ushorts)

    // ds_read lane geometry: element (r, quad*8) at r*32 + ((quad ^ (r16&3))*8)
    const int cx8 = ((quad ^ (r16 & 3)) << 3);
    const int arow0 = wm * 128 + r16;
    const int brow0 = wn * 64 + r16;

    floatx4 acc[8][4];
    #pragma unroll
    for (int i = 0; i < 8; i++)
        #pragma unroll
        for (int j = 0; j < 4; j++) acc[i][j] = (floatx4)(0.f);

    // prologue: tile0 fully + tile1 {B0,A0,B1}; 3 newest halves stay in flight
    STAGE(1, 0, 0); STAGE(0, 0, 0); STAGE(1, 1, 0); STAGE(0, 1, 0);
    STAGE(1, 0, 1); STAGE(0, 0, 1); STAGE(1, 1, 1);
    asm volatile("s_waitcnt vmcnt(6)" ::: "memory");
    __builtin_amdgcn_s_barrier();

    #pragma unroll 2
    for (int tt = 0; tt < 64; ++tt) {
        const int buf = tt & 1;
        short8 a[4], b[4];

        RD_A(0, 0); RD_B(0);
        if (tt < 63) STAGE(0, 1, tt + 1);
        MFMA_PH(0);

        RD_A(1, 0);
        if (tt < 62) STAGE(1, 0, tt + 2);
        MFMA_PH(1);

        RD_A(0, 1); RD_B(1);
        if (tt < 62) STAGE(0, 0, tt + 2);
        MFMA_PH(0);

        RD_A(1, 1);
        if (tt < 62) STAGE(1, 1, tt + 2);
        if (tt < 62)       asm volatile("s_waitcnt vmcnt(6)" ::: "memory");
        else if (tt == 62) asm volatile("s_waitcnt vmcnt(0)" ::: "memory");
        MFMA_PH(1);
    }

    // epilogue: identical permuted C mapping (crow = k*256 + n) + bias
    #pragma unroll
    for (int mi = 0; mi < 8; mi++) {
        const int rp0 = m0 + wm * 128 + mi * 16 + quad * 4;
        #pragma unroll
        for (int ni = 0; ni < 4; ni++) {
            const int col = n0 + wn * 64 + ni * 16 + r16;
            const float bv = bias[col];
            #pragma unroll
            for (int r = 0; r < 4; r++) {
                const int rp = rp0 + r;
                const int crow = ((rp & 63) << 8) | (rp >> 6);
                C[(size_t)crow * 4096 + col] = acc[mi][ni][r] + bv;
            }
        }
    }
}

// ---------------- launch ----------------
extern "C" void kernel_launch(void* const* d_in, const int* in_sizes, int n_in,
                              void* d_out, int out_size, void* d_ws, size_t ws_size,
                              hipStream_t stream) {
    const float* values = (const float*)d_in[0];
    const float* keys   = (const float*)d_in[1];
    const float* query  = (const float*)d_in[2];
    const int*   mask   = (const int*)d_in[3];
    const float* w_out  = (const float*)d_in[4];
    const float* b_out  = (const float*)d_in[5];
    float* out = (float*)d_out;

    char* ws = (char*)d_ws;
    unsigned short* P  = (unsigned short*)ws;                    // 134,217,728 B (P then F)
    unsigned short* wb = (unsigned short*)(ws + 134217728);      //  33,554,432 B
    float* vsum        = (float*)(ws + 167772160);               //   4,194,304 B
    float* denom       = (float*)(ws + 171966464);               //   1,048,576 B

    cast_w<<<16384, 256, 0, stream>>>(w_out, wb);
    vsum_k<<<4096, 256, 0, stream>>>(values, vsum);
    energy_k2<<<dim3(4, 256), 256, 0, stream>>>(query, keys, mask, P);
    denom_k<<<256, 256, 0, stream>>>(P, denom);
    pv_k<<<dim3(16, 256), 256, 0, stream>>>(P, denom, vsum, P);
    gemm_bt2<<<1024, 512, 0, stream>>>(P, wb, b_out, out);
}